// Round 1
// baseline (1533.681 us; speedup 1.0000x reference)
//
#include <hip/hip_runtime.h>
#include <cstdint>

#define NN 4096
#define EE 131072
#define BB 64

// ---------------------------------------------------------------------------
// Graph preprocessing: degree histogram, scan -> CSR by dst, fill cols/vals
// ---------------------------------------------------------------------------
__global__ void k_deg_hist(const int* __restrict__ src, const int* __restrict__ dst,
                           const float* __restrict__ ew, float* __restrict__ deg,
                           int* __restrict__ cnt) {
    int e = blockIdx.x * blockDim.x + threadIdx.x;
    if (e >= EE) return;
    atomicAdd(&deg[src[e]], ew[e]);
    atomicAdd(&cnt[dst[e]], 1);
}

__global__ __launch_bounds__(1024) void k_scan(const int* __restrict__ cnt,
                                               int* __restrict__ rowptr,
                                               int* __restrict__ cursor) {
    __shared__ int s[1024];
    int tid = threadIdx.x;
    int v0 = cnt[tid * 4 + 0], v1 = cnt[tid * 4 + 1];
    int v2 = cnt[tid * 4 + 2], v3 = cnt[tid * 4 + 3];
    int sum = v0 + v1 + v2 + v3;
    s[tid] = sum;
    __syncthreads();
    for (int off = 1; off < 1024; off <<= 1) {
        int t = (tid >= off) ? s[tid - off] : 0;
        __syncthreads();
        s[tid] += t;
        __syncthreads();
    }
    int excl = s[tid] - sum;  // exclusive prefix of this thread's 4 elements
    rowptr[tid * 4 + 0] = excl; cursor[tid * 4 + 0] = excl; excl += v0;
    rowptr[tid * 4 + 1] = excl; cursor[tid * 4 + 1] = excl; excl += v1;
    rowptr[tid * 4 + 2] = excl; cursor[tid * 4 + 2] = excl; excl += v2;
    rowptr[tid * 4 + 3] = excl; cursor[tid * 4 + 3] = excl; excl += v3;
    if (tid == 1023) rowptr[4096] = excl;
}

__global__ void k_fill(const int* __restrict__ src, const int* __restrict__ dst,
                       const float* __restrict__ ew, const float* __restrict__ deg,
                       int* __restrict__ cursor, int* __restrict__ cols,
                       float* __restrict__ vals) {
    int e = blockIdx.x * blockDim.x + threadIdx.x;
    if (e >= EE) return;
    int s = src[e], d = dst[e];
    int pos = atomicAdd(&cursor[d], 1);
    float ds = deg[s], dd = deg[d];
    float is = ds > 0.f ? rsqrtf(fmaxf(ds, 1e-30f)) : 0.f;
    float id = dd > 0.f ? rsqrtf(fmaxf(dd, 1e-30f)) : 0.f;
    cols[pos] = s;
    vals[pos] = -(is * ew[e] * id);
}

// ---------------------------------------------------------------------------
// Transpose x [B,N] -> X0 [N,B]  (layer-1 input, width 64)
// ---------------------------------------------------------------------------
__global__ __launch_bounds__(256) void k_transpose_x(const float* __restrict__ x,
                                                     float* __restrict__ X0) {
    __shared__ float s[64 * 65];
    int n0 = blockIdx.x * 64;
    for (int idx = threadIdx.x; idx < 4096; idx += 256) {
        int b = idx >> 6, nl = idx & 63;
        s[nl * 65 + b] = x[(size_t)b * NN + n0 + nl];
    }
    __syncthreads();
    for (int idx = threadIdx.x; idx < 4096; idx += 256) {
        int nl = idx >> 6, b = idx & 63;
        X0[(size_t)(n0 + nl) * 64 + b] = s[nl * 65 + b];
    }
}

// ---------------------------------------------------------------------------
// SpMM narrow (width 64, layer 1): one 64-thread block per row
// Tout = alpha * (L @ Zin) - (useprev ? Tprev : 0)
// ---------------------------------------------------------------------------
__global__ __launch_bounds__(64) void k_spmm_narrow(const int* __restrict__ rowptr,
                                                    const int* __restrict__ cols,
                                                    const float* __restrict__ vals,
                                                    const float* __restrict__ Zin,
                                                    const float* __restrict__ Tprev,
                                                    float* __restrict__ Tout,
                                                    float alpha, int useprev) {
    int n = blockIdx.x;
    int lane = threadIdx.x;
    int start = rowptr[n], end = rowptr[n + 1];
    float acc = 0.f;
    for (int e = start; e < end; ++e) {
        acc += vals[e] * Zin[((size_t)cols[e] << 6) + lane];
    }
    size_t o = ((size_t)n << 6) + lane;
    float r = alpha * acc;
    if (useprev) r -= Tprev[o];
    Tout[o] = r;
}

// ---------------------------------------------------------------------------
// SpMM wide (width 2048): wave-per-row, column-chunked (8 chunks of 256 floats)
// chunk = blockIdx % 8  -> with round-robin block->XCD dispatch, each XCD's L2
// only sees a 4MB column slice of Zin.
// ---------------------------------------------------------------------------
__global__ __launch_bounds__(256) void k_spmm_wide(const int* __restrict__ rowptr,
                                                   const int* __restrict__ cols,
                                                   const float* __restrict__ vals,
                                                   const float* __restrict__ Zin,
                                                   const float* __restrict__ Tprev,
                                                   float* __restrict__ Tout,
                                                   float alpha, int useprev) {
    int chunk = blockIdx.x & 7;
    int rowblk = blockIdx.x >> 3;
    int wave = threadIdx.x >> 6;
    int lane = threadIdx.x & 63;
    int n = rowblk * 4 + wave;
    int start = rowptr[n], end = rowptr[n + 1];
    int col0 = chunk * 256 + lane * 4;
    float4 acc = make_float4(0.f, 0.f, 0.f, 0.f);
    for (int e = start; e < end; ++e) {
        float v = vals[e];
        const float4 z = *reinterpret_cast<const float4*>(Zin + ((size_t)cols[e] << 11) + col0);
        acc.x += v * z.x; acc.y += v * z.y; acc.z += v * z.z; acc.w += v * z.w;
    }
    size_t o = ((size_t)n << 11) + col0;
    float4 r;
    r.x = alpha * acc.x; r.y = alpha * acc.y; r.z = alpha * acc.z; r.w = alpha * acc.w;
    if (useprev) {
        const float4 p = *reinterpret_cast<const float4*>(Tprev + o);
        r.x -= p.x; r.y -= p.y; r.z -= p.z; r.w -= p.w;
    }
    *reinterpret_cast<float4*>(Tout + o) = r;
}

// ---------------------------------------------------------------------------
// Feature GEMM: OUT[n, b*COUT+co] (+)= sum_ci T[n, b*CIN+ci] * W[ci*COUT+co]
// mode 0: write, 1: accumulate, 2: accumulate + bias + relu
// ---------------------------------------------------------------------------
template <int CIN, int COUT>
__global__ __launch_bounds__(256) void feat_gemm(const float* __restrict__ T,
                                                 const float* __restrict__ W,
                                                 const float* __restrict__ bias,
                                                 float* __restrict__ OUT, int mode) {
    constexpr int WIN = BB * CIN;
    constexpr int WOUT = BB * COUT;
    constexpr int OPT = (WOUT + 255) / 256;  // 8 for COUT=32, 1 for COUT=4
    __shared__ float sT[CIN * 65];
    __shared__ float sW[CIN * COUT];
    int n = blockIdx.x;
    int tid = threadIdx.x;
    for (int idx = tid; idx < WIN; idx += 256) {
        int b = idx / CIN, ci = idx % CIN;
        sT[ci * 65 + b] = T[(size_t)n * WIN + idx];
    }
    for (int idx = tid; idx < CIN * COUT; idx += 256) sW[idx] = W[idx];
    __syncthreads();
    int col0 = tid * OPT;
    if (col0 < WOUT) {
        int b = col0 / COUT, co0 = col0 % COUT;
        float acc[OPT];
#pragma unroll
        for (int j = 0; j < OPT; ++j) acc[j] = 0.f;
#pragma unroll
        for (int ci = 0; ci < CIN; ++ci) {
            float t = sT[ci * 65 + b];
#pragma unroll
            for (int j = 0; j < OPT; ++j) acc[j] += t * sW[ci * COUT + co0 + j];
        }
        size_t o = (size_t)n * WOUT + col0;
        if (mode == 0) {
#pragma unroll
            for (int j = 0; j < OPT; ++j) OUT[o + j] = acc[j];
        } else if (mode == 1) {
#pragma unroll
            for (int j = 0; j < OPT; ++j) OUT[o + j] += acc[j];
        } else {
#pragma unroll
            for (int j = 0; j < OPT; ++j) {
                float r = OUT[o + j] + acc[j] + bias[co0 + j];
                OUT[o + j] = r > 0.f ? r : 0.f;
            }
        }
    }
}

// ---------------------------------------------------------------------------
// FC1: out[b,j] += sum_k h[b,k] * fw1[k,j]; h[b, n*4+c] = H5[n, b*4+c]
// split-K over 128 blocks (128 k-rows each), atomic accumulate
// ---------------------------------------------------------------------------
__global__ __launch_bounds__(256) void k_fc1(const float* __restrict__ H5,
                                             const float* __restrict__ fw1,
                                             float* __restrict__ fc1out) {
    __shared__ float hT[128 * 65];  // [kk][b]
    __shared__ float wS[32 * 128];
    int tid = threadIdx.x;
    int n0 = blockIdx.x * 32;  // 32 nodes -> 128 k rows
    for (int idx = tid; idx < 8192; idx += 256) {
        int n_l = idx >> 8;
        int rem = idx & 255;
        int b = rem >> 2, c = rem & 3;
        int kk = n_l * 4 + c;
        hT[kk * 65 + b] = H5[(size_t)(n0 + n_l) * 256 + rem];
    }
    float acc[8][4];
#pragma unroll
    for (int i = 0; i < 8; ++i)
#pragma unroll
        for (int j = 0; j < 4; ++j) acc[i][j] = 0.f;
    int bq = tid >> 5;   // b = bq*8 + bi
    int jq = tid & 31;   // j = jq*4 + ji
    for (int kb = 0; kb < 128; kb += 32) {
        __syncthreads();
        for (int idx = tid; idx < 4096; idx += 256) {
            int kl = idx >> 7, j = idx & 127;
            wS[idx] = fw1[(size_t)(n0 * 4 + kb + kl) * 128 + j];
        }
        __syncthreads();
        for (int kl = 0; kl < 32; ++kl) {
            int kk = kb + kl;
            float4 w = *reinterpret_cast<const float4*>(&wS[kl * 128 + jq * 4]);
#pragma unroll
            for (int bi = 0; bi < 8; ++bi) {
                float h = hT[kk * 65 + bq * 8 + bi];
                acc[bi][0] += h * w.x;
                acc[bi][1] += h * w.y;
                acc[bi][2] += h * w.z;
                acc[bi][3] += h * w.w;
            }
        }
    }
#pragma unroll
    for (int bi = 0; bi < 8; ++bi)
#pragma unroll
        for (int ji = 0; ji < 4; ++ji)
            atomicAdd(&fc1out[(bq * 8 + bi) * 128 + jq * 4 + ji], acc[bi][ji]);
}

// ---------------------------------------------------------------------------
// FC2 + FC3 fused (per batch row). No relu between fc layers (per reference).
// ---------------------------------------------------------------------------
__global__ __launch_bounds__(128) void k_fc23(const float* __restrict__ fc1out,
                                              const float* __restrict__ fb1,
                                              const float* __restrict__ fw2,
                                              const float* __restrict__ fb2,
                                              const float* __restrict__ fw3,
                                              const float* __restrict__ fb3,
                                              float* __restrict__ out) {
    int b = blockIdx.x;
    int j = threadIdx.x;
    __shared__ float r[128];
    __shared__ float s1[128];
    r[j] = fc1out[b * 128 + j] + fb1[j];
    __syncthreads();
    float acc = fb2[j];
    for (int i = 0; i < 128; ++i) acc += r[i] * fw2[i * 128 + j];
    s1[j] = acc;
    __syncthreads();
    if (j < 9) {
        float a2 = fb3[j];
        for (int i = 0; i < 128; ++i) a2 += s1[i] * fw3[i * 9 + j];
        out[b * 9 + j] = a2;
    }
}

// ---------------------------------------------------------------------------
extern "C" void kernel_launch(void* const* d_in, const int* in_sizes, int n_in,
                              void* d_out, int out_size, void* d_ws, size_t ws_size,
                              hipStream_t stream) {
    const float* x   = (const float*)d_in[0];
    const int*   src = (const int*)d_in[1];
    const int*   dst = (const int*)d_in[2];
    const float* ew  = (const float*)d_in[3];
    const float* w1  = (const float*)d_in[4];
    const float* b1  = (const float*)d_in[5];
    const float* w2  = (const float*)d_in[6];
    const float* b2  = (const float*)d_in[7];
    const float* w3  = (const float*)d_in[8];
    const float* b3  = (const float*)d_in[9];
    const float* w4  = (const float*)d_in[10];
    const float* b4  = (const float*)d_in[11];
    const float* w5  = (const float*)d_in[12];
    const float* b5  = (const float*)d_in[13];
    const float* fw1 = (const float*)d_in[14];
    const float* fb1 = (const float*)d_in[15];
    const float* fw2 = (const float*)d_in[16];
    const float* fb2 = (const float*)d_in[17];
    const float* fw3 = (const float*)d_in[18];
    const float* fb3 = (const float*)d_in[19];
    float* out = (float*)d_out;

    char* p = (char*)d_ws;
    const size_t XBYTES = (size_t)NN * 2048 * 4;  // 32 MB
    float* X0 = (float*)(p + 0 * XBYTES);
    float* X1 = (float*)(p + 1 * XBYTES);
    float* X2 = (float*)(p + 2 * XBYTES);
    float* X3 = (float*)(p + 3 * XBYTES);
    size_t off = 4 * XBYTES;
    float* deg    = (float*)(p + off); off += (size_t)NN * 4;
    int*   cnt    = (int*)(p + off);   off += (size_t)NN * 4;
    int*   cursor = (int*)(p + off);   off += (size_t)NN * 4;
    int*   rowptr = (int*)(p + off);   off += (size_t)(NN + 4) * 4;
    int*   cols   = (int*)(p + off);   off += (size_t)EE * 4;
    float* vals   = (float*)(p + off); off += (size_t)EE * 4;
    float* fc1o   = (float*)(p + off); off += (size_t)BB * 128 * 4;
    if (off > ws_size) return;  // insufficient workspace — bail rather than corrupt

    hipMemsetAsync(deg, 0, NN * 4, stream);
    hipMemsetAsync(cnt, 0, NN * 4, stream);
    hipMemsetAsync(fc1o, 0, BB * 128 * 4, stream);

    k_deg_hist<<<EE / 256, 256, 0, stream>>>(src, dst, ew, deg, cnt);
    k_scan<<<1, 1024, 0, stream>>>(cnt, rowptr, cursor);
    k_fill<<<EE / 256, 256, 0, stream>>>(src, dst, ew, deg, cursor, cols, vals);
    k_transpose_x<<<NN / 64, 256, 0, stream>>>(x, X0);

    // ------------------- layer 1 (CIN=1, width 64) -> OUT X3 (width 2048)
    feat_gemm<1, 32><<<NN, 256, 0, stream>>>(X0, w1 + 0, nullptr, X3, 0);
    k_spmm_narrow<<<NN, 64, 0, stream>>>(rowptr, cols, vals, X0, nullptr, X1, 1.f, 0);
    feat_gemm<1, 32><<<NN, 256, 0, stream>>>(X1, w1 + 32, nullptr, X3, 1);
    k_spmm_narrow<<<NN, 64, 0, stream>>>(rowptr, cols, vals, X1, X0, X2, 2.f, 1);
    feat_gemm<1, 32><<<NN, 256, 0, stream>>>(X2, w1 + 64, nullptr, X3, 1);
    k_spmm_narrow<<<NN, 64, 0, stream>>>(rowptr, cols, vals, X2, X1, X0, 2.f, 1);
    feat_gemm<1, 32><<<NN, 256, 0, stream>>>(X0, w1 + 96, b1, X3, 2);

    // ------------------- layers 2-4 (CIN=32 -> COUT=32)
    auto run32 = [&](const float* Hin, float* T1, float* T2, float* T3, float* OUT,
                     const float* W, const float* B) {
        feat_gemm<32, 32><<<NN, 256, 0, stream>>>(Hin, W, nullptr, OUT, 0);
        k_spmm_wide<<<(NN / 4) * 8, 256, 0, stream>>>(rowptr, cols, vals, Hin, nullptr, T1, 1.f, 0);
        feat_gemm<32, 32><<<NN, 256, 0, stream>>>(T1, W + 1024, nullptr, OUT, 1);
        k_spmm_wide<<<(NN / 4) * 8, 256, 0, stream>>>(rowptr, cols, vals, T1, Hin, T2, 2.f, 1);
        feat_gemm<32, 32><<<NN, 256, 0, stream>>>(T2, W + 2048, nullptr, OUT, 1);
        k_spmm_wide<<<(NN / 4) * 8, 256, 0, stream>>>(rowptr, cols, vals, T2, T1, T3, 2.f, 1);
        feat_gemm<32, 32><<<NN, 256, 0, stream>>>(T3, W + 3072, B, OUT, 2);
    };
    run32(X3, X0, X1, X3, X2, w2, b2);  // Hin=X3, T3 overwrites X3, OUT=X2
    run32(X2, X3, X0, X2, X1, w3, b3);
    run32(X1, X2, X3, X1, X0, w4, b4);

    // ------------------- layer 5 (CIN=32 -> COUT=4), OUT X3 (width 256)
    feat_gemm<32, 4><<<NN, 256, 0, stream>>>(X0, w5 + 0, nullptr, X3, 0);
    k_spmm_wide<<<(NN / 4) * 8, 256, 0, stream>>>(rowptr, cols, vals, X0, nullptr, X1, 1.f, 0);
    feat_gemm<32, 4><<<NN, 256, 0, stream>>>(X1, w5 + 128, nullptr, X3, 1);
    k_spmm_wide<<<(NN / 4) * 8, 256, 0, stream>>>(rowptr, cols, vals, X1, X0, X2, 2.f, 1);
    feat_gemm<32, 4><<<NN, 256, 0, stream>>>(X2, w5 + 256, nullptr, X3, 1);
    k_spmm_wide<<<(NN / 4) * 8, 256, 0, stream>>>(rowptr, cols, vals, X2, X1, X0, 2.f, 1);
    feat_gemm<32, 4><<<NN, 256, 0, stream>>>(X0, w5 + 384, b5, X3, 2);

    // ------------------- FC head
    k_fc1<<<128, 256, 0, stream>>>(X3, fw1, fc1o);
    k_fc23<<<BB, 128, 0, stream>>>(fc1o, fb1, fw2, fb2, fw3, fb3, out);
}

// Round 3
// 1083.950 us; speedup vs baseline: 1.4149x; 1.4149x over previous
//
#include <hip/hip_runtime.h>
#include <cstdint>

#define NN 4096
#define EE 131072
#define BB 64

typedef float f4 __attribute__((ext_vector_type(4)));

// ---------------------------------------------------------------------------
// Graph preprocessing
// ---------------------------------------------------------------------------
__global__ void k_deg_hist(const int* __restrict__ src, const int* __restrict__ dst,
                           const float* __restrict__ ew, float* __restrict__ deg,
                           int* __restrict__ cnt) {
    int e = blockIdx.x * blockDim.x + threadIdx.x;
    if (e >= EE) return;
    atomicAdd(&deg[src[e]], ew[e]);
    atomicAdd(&cnt[dst[e]], 1);
}

__global__ __launch_bounds__(1024) void k_scan(const int* __restrict__ cnt,
                                               int* __restrict__ rowptr,
                                               int* __restrict__ cursor) {
    __shared__ int s[1024];
    int tid = threadIdx.x;
    int v0 = cnt[tid * 4 + 0], v1 = cnt[tid * 4 + 1];
    int v2 = cnt[tid * 4 + 2], v3 = cnt[tid * 4 + 3];
    int sum = v0 + v1 + v2 + v3;
    s[tid] = sum;
    __syncthreads();
    for (int off = 1; off < 1024; off <<= 1) {
        int t = (tid >= off) ? s[tid - off] : 0;
        __syncthreads();
        s[tid] += t;
        __syncthreads();
    }
    int excl = s[tid] - sum;
    rowptr[tid * 4 + 0] = excl; cursor[tid * 4 + 0] = excl; excl += v0;
    rowptr[tid * 4 + 1] = excl; cursor[tid * 4 + 1] = excl; excl += v1;
    rowptr[tid * 4 + 2] = excl; cursor[tid * 4 + 2] = excl; excl += v2;
    rowptr[tid * 4 + 3] = excl; cursor[tid * 4 + 3] = excl; excl += v3;
    if (tid == 1023) rowptr[4096] = excl;
}

__global__ void k_fill(const int* __restrict__ src, const int* __restrict__ dst,
                       const float* __restrict__ ew, const float* __restrict__ deg,
                       int* __restrict__ cursor, int* __restrict__ cols,
                       float* __restrict__ vals) {
    int e = blockIdx.x * blockDim.x + threadIdx.x;
    if (e >= EE) return;
    int s = src[e], d = dst[e];
    int pos = atomicAdd(&cursor[d], 1);
    float ds = deg[s], dd = deg[d];
    float is = ds > 0.f ? rsqrtf(fmaxf(ds, 1e-30f)) : 0.f;
    float id = dd > 0.f ? rsqrtf(fmaxf(dd, 1e-30f)) : 0.f;
    cols[pos] = s;
    vals[pos] = -(is * ew[e] * id);
}

// ---------------------------------------------------------------------------
// Transpose x [B,N] -> X0 [N,B]
// ---------------------------------------------------------------------------
__global__ __launch_bounds__(256) void k_transpose_x(const float* __restrict__ x,
                                                     float* __restrict__ X0) {
    __shared__ float s[64 * 65];
    int n0 = blockIdx.x * 64;
    for (int idx = threadIdx.x; idx < 4096; idx += 256) {
        int b = idx >> 6, nl = idx & 63;
        s[nl * 65 + b] = x[(size_t)b * NN + n0 + nl];
    }
    __syncthreads();
    for (int idx = threadIdx.x; idx < 4096; idx += 256) {
        int nl = idx >> 6, b = idx & 63;
        X0[(size_t)(n0 + nl) * 64 + b] = s[nl * 65 + b];
    }
}

// ---------------------------------------------------------------------------
// SpMM narrow (width 64, layer 1), x4 unrolled gather loop
// ---------------------------------------------------------------------------
__global__ __launch_bounds__(64) void k_spmm_narrow(const int* __restrict__ rowptr,
                                                    const int* __restrict__ cols,
                                                    const float* __restrict__ vals,
                                                    const float* __restrict__ Zin,
                                                    const float* __restrict__ Tprev,
                                                    float* __restrict__ Tout,
                                                    float alpha, int useprev) {
    int n = blockIdx.x;
    int lane = threadIdx.x;
    int start = rowptr[n], end = rowptr[n + 1];
    float acc = 0.f;
    int e = start;
    int n4 = start + ((end - start) & ~3);
    for (; e < n4; e += 4) {
        int c0 = cols[e], c1 = cols[e + 1], c2 = cols[e + 2], c3 = cols[e + 3];
        float v0 = vals[e], v1 = vals[e + 1], v2 = vals[e + 2], v3 = vals[e + 3];
        float z0 = Zin[((size_t)c0 << 6) + lane];
        float z1 = Zin[((size_t)c1 << 6) + lane];
        float z2 = Zin[((size_t)c2 << 6) + lane];
        float z3 = Zin[((size_t)c3 << 6) + lane];
        acc += v0 * z0 + v1 * z1 + v2 * z2 + v3 * z3;
    }
    for (; e < end; ++e) acc += vals[e] * Zin[((size_t)cols[e] << 6) + lane];
    size_t o = ((size_t)n << 6) + lane;
    float r = alpha * acc;
    if (useprev) r -= Tprev[o];
    Tout[o] = r;
}

// ---------------------------------------------------------------------------
// Fused wide SpMM + Chebyshev recurrence + channel-mix epilogue.
//   U   = L_hat @ Zg                    (gathered, x4-unrolled)
//   T   = Pown ? (2U - Pown) : U        (non-temporal Pown read)
//   Tout = T                            (optional, non-temporal write)
//   OUT (+)= T*Wk [+ Xown*W0] [+ bias, relu]   per `mode`
// Layout: width 2048 = 64 batches x 32 ch, col = b*32 + c.
// chunk = blockIdx & 7 == XCD (round-robin dispatch) -> 4MB L2 slice locality.
// ---------------------------------------------------------------------------
template <int COUT>
__global__ __launch_bounds__(256) void k_fused_spmm(
    const int* __restrict__ rowptr, const int* __restrict__ cols,
    const float* __restrict__ vals,
    const float* __restrict__ Zg,    // gather input [N][2048]
    const float* __restrict__ Pown,  // recurrence prev own-row (or null -> alpha=1)
    const float* __restrict__ Xown,  // extra own-row for W0 term (or null)
    const float* __restrict__ Wk,    // [32*COUT]
    const float* __restrict__ W0,    // [32*COUT] or null
    const float* __restrict__ bias,  // [COUT] for mode 2
    float* __restrict__ OUT,
    float* __restrict__ Tout,        // [N][2048] or null
    int mode)                        // 0 write, 1 accum, 2 accum+bias+relu
{
    __shared__ float sW[32 * COUT];
    __shared__ float sW0[32 * COUT];
    __shared__ float sT[4][264];

    int chunk = blockIdx.x & 7;
    int rowblk = blockIdx.x >> 3;
    int wave = threadIdx.x >> 6;
    int lane = threadIdx.x & 63;
    int n = rowblk * 4 + wave;
    int col0 = chunk * 256 + lane * 4;
    int tid = threadIdx.x;

    // strided loads: 32*COUT may exceed blockDim (1024 for COUT=32)
    for (int idx = tid; idx < 32 * COUT; idx += 256) sW[idx] = Wk[idx];
    if (W0) {
        for (int idx = tid; idx < 32 * COUT; idx += 256) sW0[idx] = W0[idx];
    }

    int start = rowptr[n], end = rowptr[n + 1];
    f4 acc = {0.f, 0.f, 0.f, 0.f};
    int e = start;
    int n4 = start + ((end - start) & ~3);
    for (; e < n4; e += 4) {
        int c0 = cols[e], c1 = cols[e + 1], c2 = cols[e + 2], c3 = cols[e + 3];
        float v0 = vals[e], v1 = vals[e + 1], v2 = vals[e + 2], v3 = vals[e + 3];
        f4 z0 = *reinterpret_cast<const f4*>(Zg + (((size_t)c0) << 11) + col0);
        f4 z1 = *reinterpret_cast<const f4*>(Zg + (((size_t)c1) << 11) + col0);
        f4 z2 = *reinterpret_cast<const f4*>(Zg + (((size_t)c2) << 11) + col0);
        f4 z3 = *reinterpret_cast<const f4*>(Zg + (((size_t)c3) << 11) + col0);
        acc += v0 * z0;
        acc += v1 * z1;
        acc += v2 * z2;
        acc += v3 * z3;
    }
    for (; e < end; ++e) {
        f4 z = *reinterpret_cast<const f4*>(Zg + (((size_t)cols[e]) << 11) + col0);
        acc += vals[e] * z;
    }

    size_t o = (((size_t)n) << 11) + col0;
    f4 t;
    if (Pown) {
        f4 pp = __builtin_nontemporal_load(reinterpret_cast<const f4*>(Pown + o));
        t = 2.f * acc - pp;
    } else {
        t = acc;
    }
    if (Tout) __builtin_nontemporal_store(t, reinterpret_cast<f4*>(Tout + o));

    // ---- epilogue: OUT (+)= T*Wk (+ Xown*W0) ----
    int g = lane >> 3, p = lane & 7;         // batch-in-chunk, channel-quad
    float* st = &sT[wave][0];
    __syncthreads();                         // sW/sW0 visible; sT safe to write
    st[g * 33 + p * 4 + 0] = t.x;
    st[g * 33 + p * 4 + 1] = t.y;
    st[g * 33 + p * 4 + 2] = t.z;
    st[g * 33 + p * 4 + 3] = t.w;
    __syncthreads();

    if constexpr (COUT == 32) {
        int co0 = p * 4;
        float o0 = 0.f, o1 = 0.f, o2 = 0.f, o3 = 0.f;
#pragma unroll
        for (int ci = 0; ci < 32; ++ci) {
            float tv = st[g * 33 + ci];
            o0 += tv * sW[ci * 32 + co0 + 0];
            o1 += tv * sW[ci * 32 + co0 + 1];
            o2 += tv * sW[ci * 32 + co0 + 2];
            o3 += tv * sW[ci * 32 + co0 + 3];
        }
        if (Xown) {
            f4 xv = __builtin_nontemporal_load(reinterpret_cast<const f4*>(Xown + o));
            __syncthreads();
            st[g * 33 + p * 4 + 0] = xv.x;
            st[g * 33 + p * 4 + 1] = xv.y;
            st[g * 33 + p * 4 + 2] = xv.z;
            st[g * 33 + p * 4 + 3] = xv.w;
            __syncthreads();
#pragma unroll
            for (int ci = 0; ci < 32; ++ci) {
                float tv = st[g * 33 + ci];
                o0 += tv * sW0[ci * 32 + co0 + 0];
                o1 += tv * sW0[ci * 32 + co0 + 1];
                o2 += tv * sW0[ci * 32 + co0 + 2];
                o3 += tv * sW0[ci * 32 + co0 + 3];
            }
        }
        f4 r = {o0, o1, o2, o3};
        f4* po = reinterpret_cast<f4*>(OUT + o);
        if (mode == 0) {
            __builtin_nontemporal_store(r, po);
        } else {
            f4 cur = *po;
            r += cur;
            if (mode == 2) {
                r.x += bias[co0 + 0]; r.y += bias[co0 + 1];
                r.z += bias[co0 + 2]; r.w += bias[co0 + 3];
                r.x = r.x > 0.f ? r.x : 0.f;
                r.y = r.y > 0.f ? r.y : 0.f;
                r.z = r.z > 0.f ? r.z : 0.f;
                r.w = r.w > 0.f ? r.w : 0.f;
            }
            __builtin_nontemporal_store(r, po);
        }
    } else {  // COUT == 4, OUT width 256: col = b*4 + co
        float o0 = 0.f;
        int gg = lane >> 2, co = lane & 3;
        if (lane < 32) {
#pragma unroll
            for (int ci = 0; ci < 32; ++ci)
                o0 += st[gg * 33 + ci] * sW[ci * 4 + co];
        }
        if (Xown) {
            f4 xv = __builtin_nontemporal_load(reinterpret_cast<const f4*>(Xown + o));
            __syncthreads();
            st[g * 33 + p * 4 + 0] = xv.x;
            st[g * 33 + p * 4 + 1] = xv.y;
            st[g * 33 + p * 4 + 2] = xv.z;
            st[g * 33 + p * 4 + 3] = xv.w;
            __syncthreads();
            if (lane < 32) {
#pragma unroll
                for (int ci = 0; ci < 32; ++ci)
                    o0 += st[gg * 33 + ci] * sW0[ci * 4 + co];
            }
        }
        if (lane < 32) {
            int oidx = n * 256 + chunk * 32 + lane;  // gg*4+co == lane
            float* po = OUT + oidx;
            if (mode == 0) {
                __builtin_nontemporal_store(o0, po);
            } else {
                float r = *po + o0;
                if (mode == 2) {
                    r += bias[co];
                    r = r > 0.f ? r : 0.f;
                }
                __builtin_nontemporal_store(r, po);
            }
        }
    }
}

// ---------------------------------------------------------------------------
// Feature GEMM for layer 1 (CIN=1): OUT[n, b*32+co] (+)= T[n,b]*W[co]
// mode 0: write, 1: accumulate, 2: accumulate + bias + relu
// ---------------------------------------------------------------------------
__global__ __launch_bounds__(256) void feat_gemm1(const float* __restrict__ T,
                                                  const float* __restrict__ W,
                                                  const float* __restrict__ bias,
                                                  float* __restrict__ OUT, int mode) {
    __shared__ float sT[64];
    __shared__ float sW[32];
    int n = blockIdx.x;
    int tid = threadIdx.x;
    if (tid < 64) sT[tid] = T[(size_t)n * 64 + tid];
    if (tid < 32) sW[tid] = W[tid];
    __syncthreads();
    // 2048 outputs / 256 threads = 8 each
    int col0 = tid * 8;
    int b = col0 >> 5;            // col = b*32+co ; 8 cols within one b (co0 = col0&31)
    int co0 = col0 & 31;
    float tv = sT[b];
    size_t o = (size_t)n * 2048 + col0;
#pragma unroll
    for (int j = 0; j < 8; ++j) {
        float a = tv * sW[co0 + j];
        if (mode == 0) OUT[o + j] = a;
        else if (mode == 1) OUT[o + j] += a;
        else {
            float r = OUT[o + j] + a + bias[co0 + j];
            OUT[o + j] = r > 0.f ? r : 0.f;
        }
    }
}

// ---------------------------------------------------------------------------
// FC1: split-K over 128 blocks, atomic accumulate. h[b, n*4+c] = H5[n, b*4+c]
// ---------------------------------------------------------------------------
__global__ __launch_bounds__(256) void k_fc1(const float* __restrict__ H5,
                                             const float* __restrict__ fw1,
                                             float* __restrict__ fc1out) {
    __shared__ float hT[128 * 65];
    __shared__ float wS[32 * 128];
    int tid = threadIdx.x;
    int n0 = blockIdx.x * 32;
    for (int idx = tid; idx < 8192; idx += 256) {
        int n_l = idx >> 8;
        int rem = idx & 255;
        int b = rem >> 2, c = rem & 3;
        int kk = n_l * 4 + c;
        hT[kk * 65 + b] = H5[(size_t)(n0 + n_l) * 256 + rem];
    }
    float acc[8][4];
#pragma unroll
    for (int i = 0; i < 8; ++i)
#pragma unroll
        for (int j = 0; j < 4; ++j) acc[i][j] = 0.f;
    int bq = tid >> 5;
    int jq = tid & 31;
    for (int kb = 0; kb < 128; kb += 32) {
        __syncthreads();
        for (int idx = tid; idx < 4096; idx += 256) {
            int kl = idx >> 7, j = idx & 127;
            wS[idx] = fw1[(size_t)(n0 * 4 + kb + kl) * 128 + j];
        }
        __syncthreads();
        for (int kl = 0; kl < 32; ++kl) {
            int kk = kb + kl;
            float4 w = *reinterpret_cast<const float4*>(&wS[kl * 128 + jq * 4]);
#pragma unroll
            for (int bi = 0; bi < 8; ++bi) {
                float h = hT[kk * 65 + bq * 8 + bi];
                acc[bi][0] += h * w.x;
                acc[bi][1] += h * w.y;
                acc[bi][2] += h * w.z;
                acc[bi][3] += h * w.w;
            }
        }
    }
#pragma unroll
    for (int bi = 0; bi < 8; ++bi)
#pragma unroll
        for (int ji = 0; ji < 4; ++ji)
            atomicAdd(&fc1out[(bq * 8 + bi) * 128 + jq * 4 + ji], acc[bi][ji]);
}

__global__ __launch_bounds__(128) void k_fc23(const float* __restrict__ fc1out,
                                              const float* __restrict__ fb1,
                                              const float* __restrict__ fw2,
                                              const float* __restrict__ fb2,
                                              const float* __restrict__ fw3,
                                              const float* __restrict__ fb3,
                                              float* __restrict__ out) {
    int b = blockIdx.x;
    int j = threadIdx.x;
    __shared__ float r[128];
    __shared__ float s1[128];
    r[j] = fc1out[b * 128 + j] + fb1[j];
    __syncthreads();
    float acc = fb2[j];
    for (int i = 0; i < 128; ++i) acc += r[i] * fw2[i * 128 + j];
    s1[j] = acc;
    __syncthreads();
    if (j < 9) {
        float a2 = fb3[j];
        for (int i = 0; i < 128; ++i) a2 += s1[i] * fw3[i * 9 + j];
        out[b * 9 + j] = a2;
    }
}

// ---------------------------------------------------------------------------
extern "C" void kernel_launch(void* const* d_in, const int* in_sizes, int n_in,
                              void* d_out, int out_size, void* d_ws, size_t ws_size,
                              hipStream_t stream) {
    const float* x   = (const float*)d_in[0];
    const int*   src = (const int*)d_in[1];
    const int*   dst = (const int*)d_in[2];
    const float* ew  = (const float*)d_in[3];
    const float* w1  = (const float*)d_in[4];
    const float* b1  = (const float*)d_in[5];
    const float* w2  = (const float*)d_in[6];
    const float* b2  = (const float*)d_in[7];
    const float* w3  = (const float*)d_in[8];
    const float* b3  = (const float*)d_in[9];
    const float* w4  = (const float*)d_in[10];
    const float* b4  = (const float*)d_in[11];
    const float* w5  = (const float*)d_in[12];
    const float* b5  = (const float*)d_in[13];
    const float* fw1 = (const float*)d_in[14];
    const float* fb1 = (const float*)d_in[15];
    const float* fw2 = (const float*)d_in[16];
    const float* fb2 = (const float*)d_in[17];
    const float* fw3 = (const float*)d_in[18];
    const float* fb3 = (const float*)d_in[19];
    float* out = (float*)d_out;

    char* p = (char*)d_ws;
    const size_t XBYTES = (size_t)NN * 2048 * 4;  // 32 MB
    float* X0 = (float*)(p + 0 * XBYTES);
    float* X1 = (float*)(p + 1 * XBYTES);
    float* X2 = (float*)(p + 2 * XBYTES);
    float* X3 = (float*)(p + 3 * XBYTES);
    size_t off = 4 * XBYTES;
    float* deg    = (float*)(p + off); off += (size_t)NN * 4;
    int*   cnt    = (int*)(p + off);   off += (size_t)NN * 4;
    int*   cursor = (int*)(p + off);   off += (size_t)NN * 4;
    int*   rowptr = (int*)(p + off);   off += (size_t)(NN + 4) * 4;
    int*   cols   = (int*)(p + off);   off += (size_t)EE * 4;
    float* vals   = (float*)(p + off); off += (size_t)EE * 4;
    float* fc1o   = (float*)(p + off); off += (size_t)BB * 128 * 4;
    if (off > ws_size) return;

    hipMemsetAsync(deg, 0, NN * 4, stream);
    hipMemsetAsync(cnt, 0, NN * 4, stream);
    hipMemsetAsync(fc1o, 0, BB * 128 * 4, stream);

    k_deg_hist<<<EE / 256, 256, 0, stream>>>(src, dst, ew, deg, cnt);
    k_scan<<<1, 1024, 0, stream>>>(cnt, rowptr, cursor);
    k_fill<<<EE / 256, 256, 0, stream>>>(src, dst, ew, deg, cursor, cols, vals);
    k_transpose_x<<<NN / 64, 256, 0, stream>>>(x, X0);

    // ------------------- layer 1 (narrow, width 64) -> H in X3 (width 2048)
    feat_gemm1<<<NN, 256, 0, stream>>>(X0, w1 + 0, nullptr, X3, 0);
    k_spmm_narrow<<<NN, 64, 0, stream>>>(rowptr, cols, vals, X0, nullptr, X1, 1.f, 0);
    feat_gemm1<<<NN, 256, 0, stream>>>(X1, w1 + 32, nullptr, X3, 1);
    k_spmm_narrow<<<NN, 64, 0, stream>>>(rowptr, cols, vals, X1, X0, X2, 2.f, 1);
    feat_gemm1<<<NN, 256, 0, stream>>>(X2, w1 + 64, nullptr, X3, 1);
    k_spmm_narrow<<<NN, 64, 0, stream>>>(rowptr, cols, vals, X2, X1, X0, 2.f, 1);
    feat_gemm1<<<NN, 256, 0, stream>>>(X0, w1 + 96, b1, X3, 2);

    const int GRID = (NN / 4) * 8;
    // ------------------- layers 2-4 (fused): H -> OUT
    auto run32 = [&](const float* H, float* T1, float* T2, float* OUT,
                     const float* W, const float* B) {
        // S1: T1 = L*H ; OUT = H*W0 + T1*W1
        k_fused_spmm<32><<<GRID, 256, 0, stream>>>(rowptr, cols, vals, H, nullptr, H,
                                                   W + 1024, W, nullptr, OUT, T1, 0);
        // S2: T2 = 2*L*T1 - H ; OUT += T2*W2
        k_fused_spmm<32><<<GRID, 256, 0, stream>>>(rowptr, cols, vals, T1, H, nullptr,
                                                   W + 2048, nullptr, nullptr, OUT, T2, 1);
        // S3: T3 = 2*L*T2 - T1 ; OUT = relu(OUT + T3*W3 + B)
        k_fused_spmm<32><<<GRID, 256, 0, stream>>>(rowptr, cols, vals, T2, T1, nullptr,
                                                   W + 3072, nullptr, B, OUT, nullptr, 2);
    };
    run32(X3, X0, X1, X2, w2, b2);
    run32(X2, X3, X0, X1, w3, b3);
    run32(X1, X2, X3, X0, w4, b4);

    // ------------------- layer 5 (COUT=4): H=X0 -> H5 in X3 (width 256)
    float* H5 = X3;
    k_fused_spmm<4><<<GRID, 256, 0, stream>>>(rowptr, cols, vals, X0, nullptr, X0,
                                              w5 + 128, w5, nullptr, H5, X1, 0);
    k_fused_spmm<4><<<GRID, 256, 0, stream>>>(rowptr, cols, vals, X1, X0, nullptr,
                                              w5 + 256, nullptr, nullptr, H5, X2, 1);
    k_fused_spmm<4><<<GRID, 256, 0, stream>>>(rowptr, cols, vals, X2, X1, nullptr,
                                              w5 + 384, nullptr, b5, H5, nullptr, 2);

    // ------------------- FC head
    k_fc1<<<128, 256, 0, stream>>>(H5, fw1, fc1o);
    k_fc23<<<BB, 128, 0, stream>>>(fc1o, fb1, fw2, fb2, fw3, fb3, out);
}

// Round 4
// 1053.548 us; speedup vs baseline: 1.4557x; 1.0289x over previous
//
#include <hip/hip_runtime.h>
#include <cstdint>

#define NN 4096
#define EE 131072
#define BB 64
#define EPAD (EE + 8 * NN)   // CSR rows padded to multiples of 8

typedef float f4 __attribute__((ext_vector_type(4)));

// ---------------------------------------------------------------------------
// Graph preprocessing
// ---------------------------------------------------------------------------
__global__ void k_deg_hist(const int* __restrict__ src, const int* __restrict__ dst,
                           const float* __restrict__ ew, float* __restrict__ deg,
                           int* __restrict__ cnt) {
    int e = blockIdx.x * blockDim.x + threadIdx.x;
    if (e >= EE) return;
    atomicAdd(&deg[src[e]], ew[e]);
    atomicAdd(&cnt[dst[e]], 1);
}

// scan of per-row counts PADDED to multiples of 8 -> uniform, tail-free SpMM loops
__global__ __launch_bounds__(1024) void k_scan(const int* __restrict__ cnt,
                                               int* __restrict__ rowptr,
                                               int* __restrict__ cursor) {
    __shared__ int s[1024];
    int tid = threadIdx.x;
    int p0 = (cnt[tid * 4 + 0] + 7) & ~7;
    int p1 = (cnt[tid * 4 + 1] + 7) & ~7;
    int p2 = (cnt[tid * 4 + 2] + 7) & ~7;
    int p3 = (cnt[tid * 4 + 3] + 7) & ~7;
    int sum = p0 + p1 + p2 + p3;
    s[tid] = sum;
    __syncthreads();
    for (int off = 1; off < 1024; off <<= 1) {
        int t = (tid >= off) ? s[tid - off] : 0;
        __syncthreads();
        s[tid] += t;
        __syncthreads();
    }
    int excl = s[tid] - sum;
    rowptr[tid * 4 + 0] = excl; cursor[tid * 4 + 0] = excl; excl += p0;
    rowptr[tid * 4 + 1] = excl; cursor[tid * 4 + 1] = excl; excl += p1;
    rowptr[tid * 4 + 2] = excl; cursor[tid * 4 + 2] = excl; excl += p2;
    rowptr[tid * 4 + 3] = excl; cursor[tid * 4 + 3] = excl; excl += p3;
    if (tid == 1023) rowptr[4096] = excl;
}

// cv[pos] = (col, val_bits); pad slots stay {0, 0.0f} from the memset
__global__ void k_fill(const int* __restrict__ src, const int* __restrict__ dst,
                       const float* __restrict__ ew, const float* __restrict__ deg,
                       int* __restrict__ cursor, int2* __restrict__ cv) {
    int e = blockIdx.x * blockDim.x + threadIdx.x;
    if (e >= EE) return;
    int s = src[e], d = dst[e];
    int pos = atomicAdd(&cursor[d], 1);
    float ds = deg[s], dd = deg[d];
    float is = ds > 0.f ? rsqrtf(fmaxf(ds, 1e-30f)) : 0.f;
    float id = dd > 0.f ? rsqrtf(fmaxf(dd, 1e-30f)) : 0.f;
    float v = -(is * ew[e] * id);
    cv[pos] = make_int2(s, __float_as_int(v));
}

// ---------------------------------------------------------------------------
// Transpose x [B,N] -> X0 [N,B]
// ---------------------------------------------------------------------------
__global__ __launch_bounds__(256) void k_transpose_x(const float* __restrict__ x,
                                                     float* __restrict__ X0) {
    __shared__ float s[64 * 65];
    int n0 = blockIdx.x * 64;
    for (int idx = threadIdx.x; idx < 4096; idx += 256) {
        int b = idx >> 6, nl = idx & 63;
        s[nl * 65 + b] = x[(size_t)b * NN + n0 + nl];
    }
    __syncthreads();
    for (int idx = threadIdx.x; idx < 4096; idx += 256) {
        int nl = idx >> 6, b = idx & 63;
        X0[(size_t)(n0 + nl) * 64 + b] = s[nl * 65 + b];
    }
}

// ---------------------------------------------------------------------------
// SpMM narrow (width 64, layer 1), tail-free x8 gather loop
// ---------------------------------------------------------------------------
__global__ __launch_bounds__(64) void k_spmm_narrow(const int* __restrict__ rowptr,
                                                    const int2* __restrict__ cv,
                                                    const float* __restrict__ Zin,
                                                    const float* __restrict__ Tprev,
                                                    float* __restrict__ Tout,
                                                    float alpha, int useprev) {
    int n = blockIdx.x;
    int lane = threadIdx.x;
    int start = rowptr[n], end = rowptr[n + 1];
    float acc = 0.f;
    for (int e = start; e < end; e += 8) {
        const int4* q = reinterpret_cast<const int4*>(cv + e);  // e%8==0 -> 16B aligned
        int4 a = q[0], b = q[1], c = q[2], d = q[3];
        float z0 = Zin[((size_t)a.x << 6) + lane];
        float z1 = Zin[((size_t)a.z << 6) + lane];
        float z2 = Zin[((size_t)b.x << 6) + lane];
        float z3 = Zin[((size_t)b.z << 6) + lane];
        float z4 = Zin[((size_t)c.x << 6) + lane];
        float z5 = Zin[((size_t)c.z << 6) + lane];
        float z6 = Zin[((size_t)d.x << 6) + lane];
        float z7 = Zin[((size_t)d.z << 6) + lane];
        acc += __int_as_float(a.y) * z0 + __int_as_float(a.w) * z1
             + __int_as_float(b.y) * z2 + __int_as_float(b.w) * z3
             + __int_as_float(c.y) * z4 + __int_as_float(c.w) * z5
             + __int_as_float(d.y) * z6 + __int_as_float(d.w) * z7;
    }
    size_t o = ((size_t)n << 6) + lane;
    float r = alpha * acc;
    if (useprev) r -= Tprev[o];
    Tout[o] = r;
}

// ---------------------------------------------------------------------------
// Fused wide SpMM + Chebyshev recurrence + channel-mix epilogue.
//   U   = L_hat @ Zg                    (gathered, x8-unrolled, tail-free)
//   T   = Pown ? (2U - Pown) : U
//   Tout = T                            (optional)
//   OUT (+)= T*Wk [+ Xown*W0] [+ bias, relu]   per `mode`
// Layout: width 2048 = 64 batches x 32 ch, col = b*32 + c.
// chunk = blockIdx & 7 == XCD (round-robin dispatch) -> 4MB L2 slice locality.
// No nontemporal hints: Tout/OUT/Pown are consumed by the next dispatch on the
// same XCD — keep them cache-resident.
// ---------------------------------------------------------------------------
template <int COUT>
__global__ __launch_bounds__(256) void k_fused_spmm(
    const int* __restrict__ rowptr, const int2* __restrict__ cv,
    const float* __restrict__ Zg,    // gather input [N][2048]
    const float* __restrict__ Pown,  // recurrence prev own-row (or null)
    const float* __restrict__ Xown,  // extra own-row for W0 term (or null)
    const float* __restrict__ Wk,    // [32*COUT]
    const float* __restrict__ W0,    // [32*COUT] or null
    const float* __restrict__ bias,  // [COUT] for mode 2
    float* __restrict__ OUT,
    float* __restrict__ Tout,        // [N][2048] or null
    int mode)                        // 0 write, 1 accum, 2 accum+bias+relu
{
    __shared__ float sW[32 * COUT];
    __shared__ float sW0[32 * COUT];
    __shared__ float sT[4][264];
    __shared__ float sX[4][264];

    int chunk = blockIdx.x & 7;
    int rowblk = blockIdx.x >> 3;
    int wave = threadIdx.x >> 6;
    int lane = threadIdx.x & 63;
    int n = rowblk * 4 + wave;
    int col0 = chunk * 256 + lane * 4;
    int tid = threadIdx.x;

    for (int idx = tid; idx < 32 * COUT; idx += 256) sW[idx] = Wk[idx];
    if (W0) {
        for (int idx = tid; idx < 32 * COUT; idx += 256) sW0[idx] = W0[idx];
    }

    int start = rowptr[n], end = rowptr[n + 1];
    f4 acc = {0.f, 0.f, 0.f, 0.f};
    for (int e = start; e < end; e += 8) {
        const int4* q = reinterpret_cast<const int4*>(cv + e);  // 16B aligned
        int4 a = q[0], b = q[1], c = q[2], d = q[3];
        f4 z0 = *reinterpret_cast<const f4*>(Zg + (((size_t)a.x) << 11) + col0);
        f4 z1 = *reinterpret_cast<const f4*>(Zg + (((size_t)a.z) << 11) + col0);
        f4 z2 = *reinterpret_cast<const f4*>(Zg + (((size_t)b.x) << 11) + col0);
        f4 z3 = *reinterpret_cast<const f4*>(Zg + (((size_t)b.z) << 11) + col0);
        f4 z4 = *reinterpret_cast<const f4*>(Zg + (((size_t)c.x) << 11) + col0);
        f4 z5 = *reinterpret_cast<const f4*>(Zg + (((size_t)c.z) << 11) + col0);
        f4 z6 = *reinterpret_cast<const f4*>(Zg + (((size_t)d.x) << 11) + col0);
        f4 z7 = *reinterpret_cast<const f4*>(Zg + (((size_t)d.z) << 11) + col0);
        acc += __int_as_float(a.y) * z0;
        acc += __int_as_float(a.w) * z1;
        acc += __int_as_float(b.y) * z2;
        acc += __int_as_float(b.w) * z3;
        acc += __int_as_float(c.y) * z4;
        acc += __int_as_float(c.w) * z5;
        acc += __int_as_float(d.y) * z6;
        acc += __int_as_float(d.w) * z7;
    }

    size_t o = (((size_t)n) << 11) + col0;
    f4 t;
    if (Pown) {
        f4 pp = *reinterpret_cast<const f4*>(Pown + o);
        t = 2.f * acc - pp;
    } else {
        t = acc;
    }
    if (Tout) *reinterpret_cast<f4*>(Tout + o) = t;

    // ---- epilogue: OUT (+)= T*Wk (+ Xown*W0), single barrier ----
    int g = lane >> 3, pq = lane & 7;        // batch-in-chunk, channel-quad
    float* st = &sT[wave][0];
    float* sx = &sX[wave][0];
    st[g * 33 + pq * 4 + 0] = t.x;
    st[g * 33 + pq * 4 + 1] = t.y;
    st[g * 33 + pq * 4 + 2] = t.z;
    st[g * 33 + pq * 4 + 3] = t.w;
    if (Xown) {
        f4 xv = *reinterpret_cast<const f4*>(Xown + o);
        sx[g * 33 + pq * 4 + 0] = xv.x;
        sx[g * 33 + pq * 4 + 1] = xv.y;
        sx[g * 33 + pq * 4 + 2] = xv.z;
        sx[g * 33 + pq * 4 + 3] = xv.w;
    }
    __syncthreads();  // covers sW/sW0 loads and sT/sX writes

    if constexpr (COUT == 32) {
        int co0 = pq * 4;
        float o0 = 0.f, o1 = 0.f, o2 = 0.f, o3 = 0.f;
#pragma unroll
        for (int ci = 0; ci < 32; ++ci) {
            float tv = st[g * 33 + ci];
            o0 += tv * sW[ci * 32 + co0 + 0];
            o1 += tv * sW[ci * 32 + co0 + 1];
            o2 += tv * sW[ci * 32 + co0 + 2];
            o3 += tv * sW[ci * 32 + co0 + 3];
        }
        if (Xown) {
#pragma unroll
            for (int ci = 0; ci < 32; ++ci) {
                float xvv = sx[g * 33 + ci];
                o0 += xvv * sW0[ci * 32 + co0 + 0];
                o1 += xvv * sW0[ci * 32 + co0 + 1];
                o2 += xvv * sW0[ci * 32 + co0 + 2];
                o3 += xvv * sW0[ci * 32 + co0 + 3];
            }
        }
        f4 r = {o0, o1, o2, o3};
        f4* po = reinterpret_cast<f4*>(OUT + o);
        if (mode == 0) {
            *po = r;
        } else {
            f4 cur = *po;
            r += cur;
            if (mode == 2) {
                r.x += bias[co0 + 0]; r.y += bias[co0 + 1];
                r.z += bias[co0 + 2]; r.w += bias[co0 + 3];
                r.x = r.x > 0.f ? r.x : 0.f;
                r.y = r.y > 0.f ? r.y : 0.f;
                r.z = r.z > 0.f ? r.z : 0.f;
                r.w = r.w > 0.f ? r.w : 0.f;
            }
            *po = r;
        }
    } else {  // COUT == 4, OUT width 256: col = b*4 + co
        if (lane < 32) {
            int gg = lane >> 2, co = lane & 3;
            float o0 = 0.f;
#pragma unroll
            for (int ci = 0; ci < 32; ++ci)
                o0 += st[gg * 33 + ci] * sW[ci * 4 + co];
            if (Xown) {
#pragma unroll
                for (int ci = 0; ci < 32; ++ci)
                    o0 += sx[gg * 33 + ci] * sW0[ci * 4 + co];
            }
            int oidx = n * 256 + chunk * 32 + lane;  // gg*4+co == lane
            float* po = OUT + oidx;
            if (mode == 0) {
                *po = o0;
            } else {
                float r = *po + o0;
                if (mode == 2) {
                    r += bias[co];
                    r = r > 0.f ? r : 0.f;
                }
                *po = r;
            }
        }
    }
}

// ---------------------------------------------------------------------------
// Feature GEMM for layer 1 (CIN=1): OUT[n, b*32+co] (+)= T[n,b]*W[co]
// ---------------------------------------------------------------------------
__global__ __launch_bounds__(256) void feat_gemm1(const float* __restrict__ T,
                                                  const float* __restrict__ W,
                                                  const float* __restrict__ bias,
                                                  float* __restrict__ OUT, int mode) {
    __shared__ float sT[64];
    __shared__ float sW[32];
    int n = blockIdx.x;
    int tid = threadIdx.x;
    if (tid < 64) sT[tid] = T[(size_t)n * 64 + tid];
    if (tid < 32) sW[tid] = W[tid];
    __syncthreads();
    int col0 = tid * 8;
    int b = col0 >> 5;
    int co0 = col0 & 31;
    float tv = sT[b];
    size_t o = (size_t)n * 2048 + col0;
#pragma unroll
    for (int j = 0; j < 8; ++j) {
        float a = tv * sW[co0 + j];
        if (mode == 0) OUT[o + j] = a;
        else if (mode == 1) OUT[o + j] += a;
        else {
            float r = OUT[o + j] + a + bias[co0 + j];
            OUT[o + j] = r > 0.f ? r : 0.f;
        }
    }
}

// ---------------------------------------------------------------------------
// FC1: split-K over 128 blocks, atomic accumulate. h[b, n*4+c] = H5[n, b*4+c]
// ---------------------------------------------------------------------------
__global__ __launch_bounds__(256) void k_fc1(const float* __restrict__ H5,
                                             const float* __restrict__ fw1,
                                             float* __restrict__ fc1out) {
    __shared__ float hT[128 * 65];
    __shared__ float wS[32 * 128];
    int tid = threadIdx.x;
    int n0 = blockIdx.x * 32;
    for (int idx = tid; idx < 8192; idx += 256) {
        int n_l = idx >> 8;
        int rem = idx & 255;
        int b = rem >> 2, c = rem & 3;
        int kk = n_l * 4 + c;
        hT[kk * 65 + b] = H5[(size_t)(n0 + n_l) * 256 + rem];
    }
    float acc[8][4];
#pragma unroll
    for (int i = 0; i < 8; ++i)
#pragma unroll
        for (int j = 0; j < 4; ++j) acc[i][j] = 0.f;
    int bq = tid >> 5;
    int jq = tid & 31;
    for (int kb = 0; kb < 128; kb += 32) {
        __syncthreads();
        for (int idx = tid; idx < 4096; idx += 256) {
            int kl = idx >> 7, j = idx & 127;
            wS[idx] = fw1[(size_t)(n0 * 4 + kb + kl) * 128 + j];
        }
        __syncthreads();
        for (int kl = 0; kl < 32; ++kl) {
            int kk = kb + kl;
            float4 w = *reinterpret_cast<const float4*>(&wS[kl * 128 + jq * 4]);
#pragma unroll
            for (int bi = 0; bi < 8; ++bi) {
                float h = hT[kk * 65 + bq * 8 + bi];
                acc[bi][0] += h * w.x;
                acc[bi][1] += h * w.y;
                acc[bi][2] += h * w.z;
                acc[bi][3] += h * w.w;
            }
        }
    }
#pragma unroll
    for (int bi = 0; bi < 8; ++bi)
#pragma unroll
        for (int ji = 0; ji < 4; ++ji)
            atomicAdd(&fc1out[(bq * 8 + bi) * 128 + jq * 4 + ji], acc[bi][ji]);
}

__global__ __launch_bounds__(128) void k_fc23(const float* __restrict__ fc1out,
                                              const float* __restrict__ fb1,
                                              const float* __restrict__ fw2,
                                              const float* __restrict__ fb2,
                                              const float* __restrict__ fw3,
                                              const float* __restrict__ fb3,
                                              float* __restrict__ out) {
    int b = blockIdx.x;
    int j = threadIdx.x;
    __shared__ float r[128];
    __shared__ float s1[128];
    r[j] = fc1out[b * 128 + j] + fb1[j];
    __syncthreads();
    float acc = fb2[j];
    for (int i = 0; i < 128; ++i) acc += r[i] * fw2[i * 128 + j];
    s1[j] = acc;
    __syncthreads();
    if (j < 9) {
        float a2 = fb3[j];
        for (int i = 0; i < 128; ++i) a2 += s1[i] * fw3[i * 9 + j];
        out[b * 9 + j] = a2;
    }
}

// ---------------------------------------------------------------------------
extern "C" void kernel_launch(void* const* d_in, const int* in_sizes, int n_in,
                              void* d_out, int out_size, void* d_ws, size_t ws_size,
                              hipStream_t stream) {
    const float* x   = (const float*)d_in[0];
    const int*   src = (const int*)d_in[1];
    const int*   dst = (const int*)d_in[2];
    const float* ew  = (const float*)d_in[3];
    const float* w1  = (const float*)d_in[4];
    const float* b1  = (const float*)d_in[5];
    const float* w2  = (const float*)d_in[6];
    const float* b2  = (const float*)d_in[7];
    const float* w3  = (const float*)d_in[8];
    const float* b3  = (const float*)d_in[9];
    const float* w4  = (const float*)d_in[10];
    const float* b4  = (const float*)d_in[11];
    const float* w5  = (const float*)d_in[12];
    const float* b5  = (const float*)d_in[13];
    const float* fw1 = (const float*)d_in[14];
    const float* fb1 = (const float*)d_in[15];
    const float* fw2 = (const float*)d_in[16];
    const float* fb2 = (const float*)d_in[17];
    const float* fw3 = (const float*)d_in[18];
    const float* fb3 = (const float*)d_in[19];
    float* out = (float*)d_out;

    char* p = (char*)d_ws;
    const size_t XBYTES = (size_t)NN * 2048 * 4;  // 32 MB
    float* X0 = (float*)(p + 0 * XBYTES);
    float* X1 = (float*)(p + 1 * XBYTES);
    float* X2 = (float*)(p + 2 * XBYTES);
    float* X3 = (float*)(p + 3 * XBYTES);
    size_t off = 4 * XBYTES;
    float* deg    = (float*)(p + off); off += (size_t)NN * 4;
    int*   cnt    = (int*)(p + off);   off += (size_t)NN * 4;
    int*   cursor = (int*)(p + off);   off += (size_t)NN * 4;
    int*   rowptr = (int*)(p + off);   off += (size_t)(NN + 4) * 4;
    int2*  cv     = (int2*)(p + off);  off += (size_t)EPAD * 8;
    float* fc1o   = (float*)(p + off); off += (size_t)BB * 128 * 4;
    if (off > ws_size) return;

    hipMemsetAsync(deg, 0, NN * 4, stream);
    hipMemsetAsync(cnt, 0, NN * 4, stream);
    hipMemsetAsync(cv, 0, (size_t)EPAD * 8, stream);  // pad edges = {col 0, val 0}
    hipMemsetAsync(fc1o, 0, BB * 128 * 4, stream);

    k_deg_hist<<<EE / 256, 256, 0, stream>>>(src, dst, ew, deg, cnt);
    k_scan<<<1, 1024, 0, stream>>>(cnt, rowptr, cursor);
    k_fill<<<EE / 256, 256, 0, stream>>>(src, dst, ew, deg, cursor, cv);
    k_transpose_x<<<NN / 64, 256, 0, stream>>>(x, X0);

    // ------------------- layer 1 (narrow, width 64) -> H in X3 (width 2048)
    feat_gemm1<<<NN, 256, 0, stream>>>(X0, w1 + 0, nullptr, X3, 0);
    k_spmm_narrow<<<NN, 64, 0, stream>>>(rowptr, cv, X0, nullptr, X1, 1.f, 0);
    feat_gemm1<<<NN, 256, 0, stream>>>(X1, w1 + 32, nullptr, X3, 1);
    k_spmm_narrow<<<NN, 64, 0, stream>>>(rowptr, cv, X1, X0, X2, 2.f, 1);
    feat_gemm1<<<NN, 256, 0, stream>>>(X2, w1 + 64, nullptr, X3, 1);
    k_spmm_narrow<<<NN, 64, 0, stream>>>(rowptr, cv, X2, X1, X0, 2.f, 1);
    feat_gemm1<<<NN, 256, 0, stream>>>(X0, w1 + 96, b1, X3, 2);

    const int GRID = (NN / 4) * 8;
    // ------------------- layers 2-4 (fused): H -> OUT
    auto run32 = [&](const float* H, float* T1, float* T2, float* OUT,
                     const float* W, const float* B) {
        // S1: T1 = L*H ; OUT = H*W0 + T1*W1
        k_fused_spmm<32><<<GRID, 256, 0, stream>>>(rowptr, cv, H, nullptr, H,
                                                   W + 1024, W, nullptr, OUT, T1, 0);
        // S2: T2 = 2*L*T1 - H ; OUT += T2*W2
        k_fused_spmm<32><<<GRID, 256, 0, stream>>>(rowptr, cv, T1, H, nullptr,
                                                   W + 2048, nullptr, nullptr, OUT, T2, 1);
        // S3: T3 = 2*L*T2 - T1 ; OUT = relu(OUT + T3*W3 + B)
        k_fused_spmm<32><<<GRID, 256, 0, stream>>>(rowptr, cv, T2, T1, nullptr,
                                                   W + 3072, nullptr, B, OUT, nullptr, 2);
    };
    run32(X3, X0, X1, X2, w2, b2);
    run32(X2, X3, X0, X1, w3, b3);
    run32(X1, X2, X3, X0, w4, b4);

    // ------------------- layer 5 (COUT=4): H=X0 -> H5 in X3 (width 256)
    float* H5 = X3;
    k_fused_spmm<4><<<GRID, 256, 0, stream>>>(rowptr, cv, X0, nullptr, X0,
                                              w5 + 128, w5, nullptr, H5, X1, 0);
    k_fused_spmm<4><<<GRID, 256, 0, stream>>>(rowptr, cv, X1, X0, nullptr,
                                              w5 + 256, nullptr, nullptr, H5, X2, 1);
    k_fused_spmm<4><<<GRID, 256, 0, stream>>>(rowptr, cv, X2, X1, nullptr,
                                              w5 + 384, nullptr, b5, H5, nullptr, 2);

    // ------------------- FC head
    k_fc1<<<128, 256, 0, stream>>>(H5, fw1, fc1o);
    k_fc23<<<BB, 128, 0, stream>>>(fc1o, fb1, fw2, fb2, fw3, fb3, out);
}